// Round 9
// baseline (430.368 us; speedup 1.0000x reference)
//
#include <hip/hip_runtime.h>
#include <hip/hip_bf16.h>
#include <cstdint>
#include <cstddef>

// ---------------- types ----------------
typedef _Float16 f16;
typedef _Float16 f16x4 __attribute__((ext_vector_type(4)));
typedef _Float16 f16x8 __attribute__((ext_vector_type(8)));
typedef float f32x4 __attribute__((ext_vector_type(4)));

#define GPTR(p) ((const __attribute__((address_space(1))) void*)(p))
#define LPTR(p) ((__attribute__((address_space(3))) void*)(p))

// Problem constants
#define T_TOK 8192
#define H_DIM 1024
#define I_DIM 512
#define N_EXP 16          // routed experts; expert 16 = shared (weight 1.0, all tokens)
#define N_ALL 17
#define TOPK 2
#define NSLOT (T_TOK * TOPK)          // 16384 routed slots
#define NSLOT_ALL (NSLOT + T_TOK)     // 24576 incl. shared

// max m-tiles (BM=128): shared 8192/128=64, routed sum ceil(c_e/128) <= 128+15=143 -> 207
#define MAX_TILES 208
#define XCD_TILES (MAX_TILES / 8)     // 26 tiles per XCD chunk

// ---------------- prep: fat grid-stride streaming, f16x8 (16B) stores ----------------
__device__ __forceinline__ void cast8(const float* __restrict__ src, f16* __restrict__ dst, int c) {
    float4 a = ((const float4*)src)[(size_t)c * 2];
    float4 b = ((const float4*)src)[(size_t)c * 2 + 1];
    f16x8 o = { (f16)a.x, (f16)a.y, (f16)a.z, (f16)a.w,
                (f16)b.x, (f16)b.y, (f16)b.z, (f16)b.w };
    *(f16x8*)(dst + (size_t)c * 8) = o;
}
__device__ __forceinline__ void split8(const float* __restrict__ src,
                                       f16* __restrict__ h, f16* __restrict__ l, int c) {
    float4 a = ((const float4*)src)[(size_t)c * 2];
    float4 b = ((const float4*)src)[(size_t)c * 2 + 1];
    float v[8] = { a.x, a.y, a.z, a.w, b.x, b.y, b.z, b.w };
    f16x8 hh, ll;
#pragma unroll
    for (int r = 0; r < 8; r++) { hh[r] = (f16)v[r]; ll[r] = (f16)(v[r] - (float)hh[r]); }
    *(f16x8*)(h + (size_t)c * 8) = hh;
    *(f16x8*)(l + (size_t)c * 8) = ll;
}
__device__ __forceinline__ void cpy8(const float* __restrict__ s, float* __restrict__ d, int c) {
    ((float4*)d)[(size_t)c * 2]     = ((const float4*)s)[(size_t)c * 2];
    ((float4*)d)[(size_t)c * 2 + 1] = ((const float4*)s)[(size_t)c * 2 + 1];
}

#define PREP_BLOCKS 2048
__global__ __launch_bounds__(256) void prep_kernel(
    const float* __restrict__ x, const float* __restrict__ gw,
    const float* __restrict__ wgu, const float* __restrict__ wsgu,
    const float* __restrict__ wd, const float* __restrict__ wsd,
    const float* __restrict__ bgu, const float* __restrict__ bsgu,
    f16* __restrict__ x_h, f16* __restrict__ x_l,
    f16* __restrict__ gw_h, f16* __restrict__ gw_l,
    f16* __restrict__ wguA, f16* __restrict__ wdA,
    float* __restrict__ biasA, int* __restrict__ counts) {
    constexpr int C_X   = 1048576;
    constexpr int C_GW  = 2048;
    constexpr int C_WGU = 2097152;
    constexpr int C_WSG = 131072;
    constexpr int C_WD  = 1048576;
    constexpr int C_WSD = 65536;
    constexpr int C_BG  = 2048;
    constexpr int C_BS  = 128;
    constexpr int NTOT  = C_X + C_GW + C_WGU + C_WSG + C_WD + C_WSD + C_BG + C_BS + 1;
    const int stride = gridDim.x * blockDim.x;
    for (int i = blockIdx.x * blockDim.x + threadIdx.x; i < NTOT; i += stride) {
        int r = i;
        if (r < C_X)  { split8(x, x_h, x_l, r); continue; }  r -= C_X;
        if (r < C_GW) { split8(gw, gw_h, gw_l, r); continue; } r -= C_GW;
        if (r < C_WGU){ cast8(wgu, wguA, r); continue; }      r -= C_WGU;
        if (r < C_WSG){ cast8(wsgu, wguA + (size_t)16 * 1024 * 1024, r); continue; } r -= C_WSG;
        if (r < C_WD) { cast8(wd, wdA, r); continue; }        r -= C_WD;
        if (r < C_WSD){ cast8(wsd, wdA + (size_t)16 * 1024 * 512, r); continue; }    r -= C_WSD;
        if (r < C_BG) { cpy8(bgu, biasA, r); continue; }      r -= C_BG;
        if (r < C_BS) { cpy8(bsgu, biasA + 16384, r); continue; } r -= C_BS;
        ((int4*)counts)[0] = (int4){0,0,0,0};
        ((int4*)counts)[1] = (int4){0,0,0,0};
        ((int4*)counts)[2] = (int4){0,0,0,0};
        ((int4*)counts)[3] = (int4){0,0,0,0};
    }
}

// ---------------- router logits via compensated MFMA: L = x @ gw^T in ~f32 precision ----
__global__ __launch_bounds__(256) void logits_kernel(
    const f16* __restrict__ Xh, const f16* __restrict__ Xl,
    const f16* __restrict__ Gh, const f16* __restrict__ Gl,
    float* __restrict__ L) {
    const int wave = threadIdx.x >> 6, lane = threadIdx.x & 63;
    const int m0 = blockIdx.x * 64 + wave * 16;
    const int qm = lane & 15, quad = lane >> 4;
    const size_t arow = (size_t)(m0 + qm) * H_DIM + quad * 8;
    const size_t brow = (size_t)qm * H_DIM + quad * 8;
    f32x4 acc = (f32x4){0.f, 0.f, 0.f, 0.f};
    const f16* ap;
    const f16* bp;
    ap = Xh + arow; bp = Gh + brow;
#pragma unroll 8
    for (int k0 = 0; k0 < H_DIM; k0 += 32) {
        acc = __builtin_amdgcn_mfma_f32_16x16x32_f16(*(const f16x8*)ap, *(const f16x8*)bp, acc, 0, 0, 0);
        ap += 32; bp += 32;
    }
    ap = Xh + arow; bp = Gl + brow;
#pragma unroll 8
    for (int k0 = 0; k0 < H_DIM; k0 += 32) {
        acc = __builtin_amdgcn_mfma_f32_16x16x32_f16(*(const f16x8*)ap, *(const f16x8*)bp, acc, 0, 0, 0);
        ap += 32; bp += 32;
    }
    ap = Xl + arow; bp = Gh + brow;
#pragma unroll 8
    for (int k0 = 0; k0 < H_DIM; k0 += 32) {
        acc = __builtin_amdgcn_mfma_f32_16x16x32_f16(*(const f16x8*)ap, *(const f16x8*)bp, acc, 0, 0, 0);
        ap += 32; bp += 32;
    }
#pragma unroll
    for (int r = 0; r < 4; r++)
        L[(size_t)(m0 + quad * 4 + r) * N_EXP + qm] = acc[r];
}

// ---------------- top-2 + renorm weight + LDS histogram ----------------
__global__ void topk_kernel(const float* __restrict__ L, int* __restrict__ sel,
                            float* __restrict__ rw, int* __restrict__ counts) {
    __shared__ int lc[N_EXP];
    const int tid = threadIdx.x;
    if (tid < N_EXP) lc[tid] = 0;
    __syncthreads();
    const int t = blockIdx.x * 256 + tid;
    float lg[16];
    const float4* lp = (const float4*)(L + (size_t)t * N_EXP);
#pragma unroll
    for (int q = 0; q < 4; q++) {
        float4 v = lp[q];
        lg[q * 4 + 0] = v.x; lg[q * 4 + 1] = v.y; lg[q * 4 + 2] = v.z; lg[q * 4 + 3] = v.w;
    }
    float best = -1e30f, sec = -1e30f; int bi = 0, si = 0;
#pragma unroll
    for (int j = 0; j < 16; j++) {
        float lj = lg[j];
        if (lj > best) { sec = best; si = bi; best = lj; bi = j; }
        else if (lj > sec) { sec = lj; si = j; }
    }
    float w1 = 1.f / (1.f + __expf(sec - best));
    sel[t * 2] = bi; sel[t * 2 + 1] = si;
    rw[t * 2] = w1;  rw[t * 2 + 1] = 1.f - w1;
    atomicAdd(&lc[bi], 1);
    atomicAdd(&lc[si], 1);
    __syncthreads();
    if (tid < N_EXP) atomicAdd(&counts[tid], lc[tid]);
}

// prefix: thread-0 scan, parallel tile-list fill. shared tiles [0,64), then experts.
__global__ void prefix_kernel(const int* __restrict__ counts, int* __restrict__ offsets,
                              int* __restrict__ cursors, int* __restrict__ tiles) {
    __shared__ int ts[17];
    __shared__ int cnt[16];
    const int tid = threadIdx.x;
    if (tid == 0) {
        int s = 0, t = 64;
        for (int e = 0; e < 16; e++) {
            int c = counts[e];
            cnt[e] = c;
            offsets[e] = s; cursors[e] = s; s += c;
            ts[e] = t; t += (c + 127) >> 7;
        }
        offsets[16] = s;                 // 16384
        offsets[17] = s + T_TOK;         // 24576
        ts[16] = t;                      // ntot
    }
    __syncthreads();
    const int ntot = ts[16];
    if (tid < 16) {
        int t0 = ts[tid], M = cnt[tid];
        for (int m0 = 0, k = 0; m0 < M; m0 += 128, k++) tiles[t0 + k] = (tid << 20) | m0;
    } else if (tid == 16) {
        for (int k = 0; k < 64; k++) tiles[k] = (16 << 20) | (k * 128);
    }
    for (int j = ntot + tid; j < MAX_TILES; j += 64) tiles[j] = -1;
}

__global__ void scatter_kernel(const int* __restrict__ sel, const float* __restrict__ rw,
                               int* __restrict__ cursors, int* __restrict__ btok,
                               float* __restrict__ bw, int* __restrict__ pos) {
    int t = blockIdx.x * blockDim.x + threadIdx.x;
    if (t >= T_TOK) return;
#pragma unroll
    for (int k = 0; k < TOPK; k++) {
        int e = sel[t * 2 + k];
        int p = atomicAdd(&cursors[e], 1);
        btok[p] = t;
        bw[p] = rw[t * 2 + k];
        pos[t * 2 + k] = p;
    }
    btok[NSLOT + t] = t;     // shared bucket: identity
    bw[NSLOT + t] = 1.f;
}

// XCD-chunked (tile, n0) decode
__device__ __forceinline__ void xcd_tile_map(int g, int& ti, int& n0i) {
    const int x = g & 7;
    const int q = g >> 3;
    ti  = x * XCD_TILES + (q >> 3);
    n0i = q & 7;
}

// counted-vmcnt before raw barrier: prefetch stays in flight across the barrier.
#define VW4_BAR() do { \
    asm volatile("s_waitcnt vmcnt(4)" ::: "memory"); \
    __builtin_amdgcn_s_barrier(); } while (0)
#define VW0_BAR() do { \
    asm volatile("s_waitcnt vmcnt(0)" ::: "memory"); \
    __builtin_amdgcn_s_barrier(); } while (0)

// ---------------- fused gate_up + SiLU*up*bw: 3-buffer depth-2, 1 barrier/K-step ----
// step t: vmcnt(4) [stage-t landed; stage-t+1 in flight] ; barrier [collective ready +
// buf(t+2 mod3)=buf(t-1 mod3) free] ; STAGE(t+2) ; COMPUTE(t). Static buffer literals.
__global__ __launch_bounds__(256, 4) void gemm_gateup_act(
    const f16* __restrict__ X,        // [T,1024]
    const f16* __restrict__ W,        // [17,1024,1024]
    const float* __restrict__ bias,   // [17,1024]
    const float* __restrict__ bw,     // [24576]
    f16* __restrict__ ACT,            // [24576,512]
    const int* __restrict__ offsets,  // [18]
    const int* __restrict__ btok,     // [24576]
    const int* __restrict__ tiles) {  // [MAX_TILES]
    constexpr int K = H_DIM;          // NT = 32 K-steps
    int ti, n0i;
    xcd_tile_map(blockIdx.x, ti, n0i);
    const int td = tiles[ti];
    if (td < 0) return;
    const int e  = td >> 20;
    const int m0 = td & 0xFFFFF;
    const int n0 = n0i * 64;
    const int base = offsets[e];
    const int M = offsets[e + 1] - base;

    const f16* Wb   = W + (size_t)e * 1024 * K;
    const float* bb = bias + (size_t)e * 1024;

    __shared__ f16 As[3][128 * 32];   // 24 KB
    __shared__ f16 Bg[3][64 * 32];    // 12 KB
    __shared__ f16 Bu[3][64 * 32];    // 12 KB -> 48 KB, 3 blocks/CU

    const int tid  = threadIdx.x;
    const int wave = tid >> 6;
    const int lane = tid & 63;
    const int srow = lane >> 2;
    const int csw  = ((lane & 3) ^ ((srow >> 1) & 3)) * 8;   // staging-side XOR swizzle

    int ar0 = m0 + wave * 32 + srow;
    int ar1 = ar0 + 16;
    int r0 = min(ar0, M - 1), r1 = min(ar1, M - 1);
    const f16* ap0 = X + (size_t)btok[base + r0] * K + csw;
    const f16* ap1 = X + (size_t)btok[base + r1] * K + csw;
    const int brow = n0 + wave * 16 + srow;
    const f16* bg0 = Wb + (size_t)brow * K + csw;
    const f16* bu0 = bg0 + (size_t)512 * K;
    f16* la0 = &As[0][(wave * 32) * 32];
    f16* la1 = la0 + 16 * 32;
    f16* lg0 = &Bg[0][(wave * 16) * 32];
    f16* lu0 = &Bu[0][(wave * 16) * 32];
    constexpr int AST = 128 * 32;
    constexpr int BST = 64 * 32;

    const int wm = (wave >> 1) * 64;
    const int wn = (wave & 1) * 32;
    const int qm = lane & 15;
    const int quad = lane >> 4;
    const int qsw = (quad ^ ((qm >> 1) & 3)) * 8;            // read-side XOR swizzle

    f32x4 accg[4][2], accu[4][2];
#pragma unroll
    for (int i = 0; i < 4; i++)
#pragma unroll
        for (int j = 0; j < 2; j++) {
            accg[i][j] = (f32x4){0.f, 0.f, 0.f, 0.f};
            accu[i][j] = (f32x4){0.f, 0.f, 0.f, 0.f};
        }

#define GU_STAGE(b) do { \
    __builtin_amdgcn_global_load_lds(GPTR(ap0), LPTR(la0 + (b) * AST), 16, 0, 0); \
    __builtin_amdgcn_global_load_lds(GPTR(ap1), LPTR(la1 + (b) * AST), 16, 0, 0); \
    __builtin_amdgcn_global_load_lds(GPTR(bg0), LPTR(lg0 + (b) * BST), 16, 0, 0); \
    __builtin_amdgcn_global_load_lds(GPTR(bu0), LPTR(lu0 + (b) * BST), 16, 0, 0); \
    ap0 += 32; ap1 += 32; bg0 += 32; bu0 += 32; } while (0)

#define GU_COMPUTE(b) do { \
    f16x8 af[4], gf[2], uf[2]; \
    _Pragma("unroll") \
    for (int i = 0; i < 4; i++) af[i] = *(const f16x8*)&As[b][(wm + i * 16 + qm) * 32 + qsw]; \
    _Pragma("unroll") \
    for (int j = 0; j < 2; j++) { \
        gf[j] = *(const f16x8*)&Bg[b][(wn + j * 16 + qm) * 32 + qsw]; \
        uf[j] = *(const f16x8*)&Bu[b][(wn + j * 16 + qm) * 32 + qsw]; \
    } \
    _Pragma("unroll") \
    for (int i = 0; i < 4; i++) \
        _Pragma("unroll") \
        for (int j = 0; j < 2; j++) { \
            accg[i][j] = __builtin_amdgcn_mfma_f32_16x16x32_f16(af[i], gf[j], accg[i][j], 0, 0, 0); \
            accu[i][j] = __builtin_amdgcn_mfma_f32_16x16x32_f16(af[i], uf[j], accu[i][j], 0, 0, 0); \
        } } while (0)

#define GU_STEP(bc, bs) do { VW4_BAR(); GU_STAGE(bs); GU_COMPUTE(bc); } while (0)

    GU_STAGE(0);
    GU_STAGE(1);                      // 8 loads in flight
    for (int t = 0; t < 30; t += 3) { // steps 0..29, stages 2..31
        GU_STEP(0, 2);
        GU_STEP(1, 0);
        GU_STEP(2, 1);
    }
    VW4_BAR(); GU_COMPUTE(0);         // step 30 (stage 31 still in flight)
    VW0_BAR(); GU_COMPUTE(1);         // step 31

    // epilogue: act = silu(g+bg)*(u+bu)*bw  (C/D: col=lane&15, row=quad*4+reg)
#pragma unroll
    for (int i = 0; i < 4; i++) {
#pragma unroll
        for (int j = 0; j < 2; j++) {
            const int colg = n0 + wn + j * 16 + qm;
            const float bvg = bb[colg];
            const float bvu = bb[colg + 512];
#pragma unroll
            for (int r = 0; r < 4; r++) {
                const int lr = wm + i * 16 + quad * 4 + r;
                const int m = m0 + lr;
                if (m < M) {
                    float g = accg[i][j][r] + bvg;
                    float u = accu[i][j][r] + bvu;
                    float sl = g / (1.f + __expf(-g));
                    ACT[(size_t)(base + m) * 512 + colg] = (f16)(sl * u * bw[base + m]);
                }
            }
        }
    }
}

// ---------------- down GEMM 128x128: 3-buffer depth-2, 1 barrier/K-step ----------------
__global__ __launch_bounds__(256, 4) void gemm_down(
    const f16* __restrict__ ACT,      // [24576,512]
    const f16* __restrict__ W,        // [17,1024,512]
    f16* __restrict__ DOWN,           // [24576,1024]
    const int* __restrict__ offsets,
    const int* __restrict__ tiles) {
    constexpr int K = I_DIM;          // NT = 16 K-steps
    int ti, n0i;
    xcd_tile_map(blockIdx.x, ti, n0i);
    const int td = tiles[ti];
    if (td < 0) return;
    const int e  = td >> 20;
    const int m0 = td & 0xFFFFF;
    const int n0 = n0i * 128;
    const int base = offsets[e];
    const int M = offsets[e + 1] - base;

    const f16* Wb = W + (size_t)e * 1024 * K;

    __shared__ f16 As[3][128 * 32];   // 24 KB
    __shared__ f16 Bs[3][128 * 32];   // 24 KB -> 48 KB, 3 blocks/CU

    const int tid  = threadIdx.x;
    const int wave = tid >> 6;
    const int lane = tid & 63;
    const int srow = lane >> 2;
    const int csw  = ((lane & 3) ^ ((srow >> 1) & 3)) * 8;

    int ar0 = m0 + wave * 32 + srow;
    int ar1 = ar0 + 16;
    int r0 = min(ar0, M - 1), r1 = min(ar1, M - 1);
    const f16* ap0 = ACT + (size_t)(base + r0) * K + csw;
    const f16* ap1 = ACT + (size_t)(base + r1) * K + csw;
    const f16* bp0 = Wb + (size_t)(n0 + wave * 32 + srow) * K + csw;
    const f16* bp1 = bp0 + (size_t)16 * K;
    f16* la0 = &As[0][(wave * 32) * 32];  f16* la1 = la0 + 16 * 32;
    f16* lb0 = &Bs[0][(wave * 32) * 32];  f16* lb1 = lb0 + 16 * 32;
    constexpr int DST = 128 * 32;

    const int wm = (wave >> 1) * 64;
    const int wn = (wave & 1) * 64;
    const int qm = lane & 15;
    const int quad = lane >> 4;
    const int qsw = (quad ^ ((qm >> 1) & 3)) * 8;

    f32x4 acc[4][4];
#pragma unroll
    for (int i = 0; i < 4; i++)
#pragma unroll
        for (int j = 0; j < 4; j++) acc[i][j] = (f32x4){0.f, 0.f, 0.f, 0.f};

#define DN_STAGE(b) do { \
    __builtin_amdgcn_global_load_lds(GPTR(ap0), LPTR(la0 + (b) * DST), 16, 0, 0); \
    __builtin_amdgcn_global_load_lds(GPTR(ap1), LPTR(la1 + (b) * DST), 16, 0, 0); \
    __builtin_amdgcn_global_load_lds(GPTR(bp0), LPTR(lb0 + (b) * DST), 16, 0, 0); \
    __builtin_amdgcn_global_load_lds(GPTR(bp1), LPTR(lb1 + (b) * DST), 16, 0, 0); \
    ap0 += 32; ap1 += 32; bp0 += 32; bp1 += 32; } while (0)

#define DN_COMPUTE(b) do { \
    f16x8 af[4], bfr[4]; \
    _Pragma("unroll") \
    for (int i = 0; i < 4; i++) af[i]  = *(const f16x8*)&As[b][(wm + i * 16 + qm) * 32 + qsw]; \
    _Pragma("unroll") \
    for (int j = 0; j < 4; j++) bfr[j] = *(const f16x8*)&Bs[b][(wn + j * 16 + qm) * 32 + qsw]; \
    _Pragma("unroll") \
    for (int i = 0; i < 4; i++) \
        _Pragma("unroll") \
        for (int j = 0; j < 4; j++) \
            acc[i][j] = __builtin_amdgcn_mfma_f32_16x16x32_f16(af[i], bfr[j], acc[i][j], 0, 0, 0); \
    } while (0)

#define DN_STEP(bc, bs) do { VW4_BAR(); DN_STAGE(bs); DN_COMPUTE(bc); } while (0)

    DN_STAGE(0);
    DN_STAGE(1);
    for (int t = 0; t < 12; t += 3) { // steps 0..11, stages 2..13
        DN_STEP(0, 2);
        DN_STEP(1, 0);
        DN_STEP(2, 1);
    }
    DN_STEP(0, 2);                    // step 12, stage 14
    DN_STEP(1, 0);                    // step 13, stage 15
    VW4_BAR(); DN_COMPUTE(2);         // step 14 (stage 15 in flight)
    VW0_BAR(); DN_COMPUTE(0);         // step 15

#pragma unroll
    for (int i = 0; i < 4; i++) {
#pragma unroll
        for (int j = 0; j < 4; j++) {
            const int col = n0 + wn + j * 16 + qm;
#pragma unroll
            for (int r = 0; r < 4; r++) {
                const int lr = wm + i * 16 + quad * 4 + r;
                const int m = m0 + lr;
                if (m < M) DOWN[(size_t)(base + m) * 1024 + col] = (f16)acc[i][j][r];
            }
        }
    }
}

// ---------------- combine: out[t] = DOWN[16384+t] + DOWN[p1] + DOWN[p2], f16x8 loads ----
__global__ void combine_kernel(const f16* __restrict__ DOWN, const int* __restrict__ pos,
                               float* __restrict__ OUT) {
    int idx = blockIdx.x * blockDim.x + threadIdx.x;
    int t = idx >> 7;             // 128 threads per token (1024 cols / 8)
    int c = (idx & 127) * 8;
    int p1 = pos[t * 2], p2 = pos[t * 2 + 1];
    f16x8 a = *(const f16x8*)(DOWN + (size_t)(NSLOT + t) * 1024 + c);
    f16x8 b = *(const f16x8*)(DOWN + (size_t)p1 * 1024 + c);
    f16x8 d = *(const f16x8*)(DOWN + (size_t)p2 * 1024 + c);
    float4 o0, o1;
    o0.x = (float)a[0] + (float)b[0] + (float)d[0];
    o0.y = (float)a[1] + (float)b[1] + (float)d[1];
    o0.z = (float)a[2] + (float)b[2] + (float)d[2];
    o0.w = (float)a[3] + (float)b[3] + (float)d[3];
    o1.x = (float)a[4] + (float)b[4] + (float)d[4];
    o1.y = (float)a[5] + (float)b[5] + (float)d[5];
    o1.z = (float)a[6] + (float)b[6] + (float)d[6];
    o1.w = (float)a[7] + (float)b[7] + (float)d[7];
    *(float4*)(OUT + (size_t)t * 1024 + c) = o0;
    *(float4*)(OUT + (size_t)t * 1024 + c + 4) = o1;
}

// ---------------- host launch ----------------
extern "C" void kernel_launch(void* const* d_in, const int* in_sizes, int n_in,
                              void* d_out, int out_size, void* d_ws, size_t ws_size,
                              hipStream_t stream) {
    const float* x    = (const float*)d_in[0];   // [8192,1024]
    const float* gw   = (const float*)d_in[1];   // [16,1024]
    const float* wgu  = (const float*)d_in[2];   // [16,1024,1024]
    const float* bgu  = (const float*)d_in[3];   // [16,1024]
    const float* wd   = (const float*)d_in[4];   // [16,1024,512]
    const float* wsgu = (const float*)d_in[5];   // [1024,1024]
    const float* bsgu = (const float*)d_in[6];   // [1024]
    const float* wsd  = (const float*)d_in[7];   // [1024,512]
    float* out = (float*)d_out;

    char* ws = (char*)d_ws;
    size_t off = 0;
    auto take = [&](size_t b) { char* p = ws + off; off = (off + b + 255) & ~(size_t)255; return p; };
    f16* x_h    = (f16*)take((size_t)T_TOK * H_DIM * 2);
    f16* x_l    = (f16*)take((size_t)T_TOK * H_DIM * 2);
    f16* gw_h   = (f16*)take((size_t)N_EXP * H_DIM * 2);
    f16* gw_l   = (f16*)take((size_t)N_EXP * H_DIM * 2);
    f16* wguA   = (f16*)take((size_t)N_ALL * 1024 * H_DIM * 2);   // [17,1024,1024]
    f16* wdA    = (f16*)take((size_t)N_ALL * 1024 * I_DIM * 2);   // [17,1024,512]
    float* biasA = (float*)take((size_t)N_ALL * 1024 * 4);        // [17,1024]
    f16* act    = (f16*)take((size_t)NSLOT_ALL * I_DIM * 2);      // [24576,512]
    f16* down   = (f16*)take((size_t)NSLOT_ALL * 1024 * 2);       // [24576,1024]
    float* logits = (float*)take((size_t)T_TOK * N_EXP * 4);
    int*   sel    = (int*)take((size_t)NSLOT * 4);
    float* rw     = (float*)take((size_t)NSLOT * 4);
    int*   btok   = (int*)take((size_t)NSLOT_ALL * 4);
    float* bw     = (float*)take((size_t)NSLOT_ALL * 4);
    int*   pos    = (int*)take((size_t)NSLOT * 4);
    int*   counts = (int*)take(64);
    int*   offs   = (int*)take(128);
    int*   curs   = (int*)take(64);
    int*   tiles  = (int*)take(MAX_TILES * 4);

    // 1) all casts/splits/copies/zeroing
    prep_kernel<<<PREP_BLOCKS, 256, 0, stream>>>(x, gw, wgu, wsgu, wd, wsd, bgu, bsgu,
                                                 x_h, x_l, gw_h, gw_l, wguA, wdA, biasA, counts);

    // 2) routing
    logits_kernel<<<T_TOK / 64, 256, 0, stream>>>(x_h, x_l, gw_h, gw_l, logits);
    topk_kernel<<<T_TOK / 256, 256, 0, stream>>>(logits, sel, rw, counts);
    prefix_kernel<<<1, 64, 0, stream>>>(counts, offs, curs, tiles);
    scatter_kernel<<<T_TOK / 256, 256, 0, stream>>>(sel, rw, curs, btok, bw, pos);

    // 3) fused gate_up + SiLU*up*bw -> ACT (XCD-chunked, depth-2 pipeline)
    gemm_gateup_act<<<dim3(MAX_TILES * 8, 1, 1), 256, 0, stream>>>(x_h, wguA, biasA, bw, act, offs, btok, tiles);

    // 4) down GEMM (128x128, depth-2 pipeline) -> DOWN (f16, coalesced)
    gemm_down<<<dim3(MAX_TILES * 8, 1, 1), 256, 0, stream>>>(act, wdA, down, offs, tiles);

    // 5) combine (f16x8-vectorized)
    combine_kernel<<<T_TOK * 1024 / 8 / 256, 256, 0, stream>>>(down, pos, out);
}

// Round 11
// 359.358 us; speedup vs baseline: 1.1976x; 1.1976x over previous
//
#include <hip/hip_runtime.h>
#include <hip/hip_bf16.h>
#include <cstdint>
#include <cstddef>

// ---------------- types ----------------
typedef _Float16 f16;
typedef _Float16 f16x4 __attribute__((ext_vector_type(4)));
typedef _Float16 f16x8 __attribute__((ext_vector_type(8)));
typedef float f32x4 __attribute__((ext_vector_type(4)));

#define GPTR(p) ((const __attribute__((address_space(1))) void*)(p))
#define LPTR(p) ((__attribute__((address_space(3))) void*)(p))

// Problem constants
#define T_TOK 8192
#define H_DIM 1024
#define I_DIM 512
#define N_EXP 16          // routed experts; expert 16 = shared (weight 1.0, all tokens)
#define N_ALL 17
#define TOPK 2
#define NSLOT (T_TOK * TOPK)          // 16384 routed slots
#define NSLOT_ALL (NSLOT + T_TOK)     // 24576 incl. shared

// max m-tiles (BM=128): shared 8192/128=64, routed sum ceil(c_e/128) <= 128+15=143 -> 207
#define MAX_TILES 208
#define XCD_TILES (MAX_TILES / 8)     // 26 tiles per XCD chunk

// ---------------- prep: fat grid-stride streaming, f16x8 (16B) stores ----------------
__device__ __forceinline__ void cast8(const float* __restrict__ src, f16* __restrict__ dst, int c) {
    float4 a = ((const float4*)src)[(size_t)c * 2];
    float4 b = ((const float4*)src)[(size_t)c * 2 + 1];
    f16x8 o = { (f16)a.x, (f16)a.y, (f16)a.z, (f16)a.w,
                (f16)b.x, (f16)b.y, (f16)b.z, (f16)b.w };
    *(f16x8*)(dst + (size_t)c * 8) = o;
}
__device__ __forceinline__ void split8(const float* __restrict__ src,
                                       f16* __restrict__ h, f16* __restrict__ l, int c) {
    float4 a = ((const float4*)src)[(size_t)c * 2];
    float4 b = ((const float4*)src)[(size_t)c * 2 + 1];
    float v[8] = { a.x, a.y, a.z, a.w, b.x, b.y, b.z, b.w };
    f16x8 hh, ll;
#pragma unroll
    for (int r = 0; r < 8; r++) { hh[r] = (f16)v[r]; ll[r] = (f16)(v[r] - (float)hh[r]); }
    *(f16x8*)(h + (size_t)c * 8) = hh;
    *(f16x8*)(l + (size_t)c * 8) = ll;
}
__device__ __forceinline__ void cpy8(const float* __restrict__ s, float* __restrict__ d, int c) {
    ((float4*)d)[(size_t)c * 2]     = ((const float4*)s)[(size_t)c * 2];
    ((float4*)d)[(size_t)c * 2 + 1] = ((const float4*)s)[(size_t)c * 2 + 1];
}

#define PREP_BLOCKS 2048
__global__ __launch_bounds__(256) void prep_kernel(
    const float* __restrict__ x, const float* __restrict__ gw,
    const float* __restrict__ wgu, const float* __restrict__ wsgu,
    const float* __restrict__ wd, const float* __restrict__ wsd,
    const float* __restrict__ bgu, const float* __restrict__ bsgu,
    f16* __restrict__ x_h, f16* __restrict__ x_l,
    f16* __restrict__ gw_h, f16* __restrict__ gw_l,
    f16* __restrict__ wguA, f16* __restrict__ wdA,
    float* __restrict__ biasA, int* __restrict__ counts) {
    constexpr int C_X   = 1048576;
    constexpr int C_GW  = 2048;
    constexpr int C_WGU = 2097152;
    constexpr int C_WSG = 131072;
    constexpr int C_WD  = 1048576;
    constexpr int C_WSD = 65536;
    constexpr int C_BG  = 2048;
    constexpr int C_BS  = 128;
    constexpr int NTOT  = C_X + C_GW + C_WGU + C_WSG + C_WD + C_WSD + C_BG + C_BS + 1;
    const int stride = gridDim.x * blockDim.x;
    for (int i = blockIdx.x * blockDim.x + threadIdx.x; i < NTOT; i += stride) {
        int r = i;
        if (r < C_X)  { split8(x, x_h, x_l, r); continue; }  r -= C_X;
        if (r < C_GW) { split8(gw, gw_h, gw_l, r); continue; } r -= C_GW;
        if (r < C_WGU){ cast8(wgu, wguA, r); continue; }      r -= C_WGU;
        if (r < C_WSG){ cast8(wsgu, wguA + (size_t)16 * 1024 * 1024, r); continue; } r -= C_WSG;
        if (r < C_WD) { cast8(wd, wdA, r); continue; }        r -= C_WD;
        if (r < C_WSD){ cast8(wsd, wdA + (size_t)16 * 1024 * 512, r); continue; }    r -= C_WSD;
        if (r < C_BG) { cpy8(bgu, biasA, r); continue; }      r -= C_BG;
        if (r < C_BS) { cpy8(bsgu, biasA + 16384, r); continue; } r -= C_BS;
        ((int4*)counts)[0] = (int4){0,0,0,0};
        ((int4*)counts)[1] = (int4){0,0,0,0};
        ((int4*)counts)[2] = (int4){0,0,0,0};
        ((int4*)counts)[3] = (int4){0,0,0,0};
    }
}

// ---------------- router logits via compensated MFMA: L = x @ gw^T in ~f32 precision ----
__global__ __launch_bounds__(256) void logits_kernel(
    const f16* __restrict__ Xh, const f16* __restrict__ Xl,
    const f16* __restrict__ Gh, const f16* __restrict__ Gl,
    float* __restrict__ L) {
    const int wave = threadIdx.x >> 6, lane = threadIdx.x & 63;
    const int m0 = blockIdx.x * 64 + wave * 16;
    const int qm = lane & 15, quad = lane >> 4;
    const size_t arow = (size_t)(m0 + qm) * H_DIM + quad * 8;
    const size_t brow = (size_t)qm * H_DIM + quad * 8;
    f32x4 acc = (f32x4){0.f, 0.f, 0.f, 0.f};
    const f16* ap;
    const f16* bp;
    ap = Xh + arow; bp = Gh + brow;
#pragma unroll 8
    for (int k0 = 0; k0 < H_DIM; k0 += 32) {
        acc = __builtin_amdgcn_mfma_f32_16x16x32_f16(*(const f16x8*)ap, *(const f16x8*)bp, acc, 0, 0, 0);
        ap += 32; bp += 32;
    }
    ap = Xh + arow; bp = Gl + brow;
#pragma unroll 8
    for (int k0 = 0; k0 < H_DIM; k0 += 32) {
        acc = __builtin_amdgcn_mfma_f32_16x16x32_f16(*(const f16x8*)ap, *(const f16x8*)bp, acc, 0, 0, 0);
        ap += 32; bp += 32;
    }
    ap = Xl + arow; bp = Gh + brow;
#pragma unroll 8
    for (int k0 = 0; k0 < H_DIM; k0 += 32) {
        acc = __builtin_amdgcn_mfma_f32_16x16x32_f16(*(const f16x8*)ap, *(const f16x8*)bp, acc, 0, 0, 0);
        ap += 32; bp += 32;
    }
#pragma unroll
    for (int r = 0; r < 4; r++)
        L[(size_t)(m0 + quad * 4 + r) * N_EXP + qm] = acc[r];
}

// ---------------- top-2 + renorm weight + LDS histogram ----------------
__global__ void topk_kernel(const float* __restrict__ L, int* __restrict__ sel,
                            float* __restrict__ rw, int* __restrict__ counts) {
    __shared__ int lc[N_EXP];
    const int tid = threadIdx.x;
    if (tid < N_EXP) lc[tid] = 0;
    __syncthreads();
    const int t = blockIdx.x * 256 + tid;
    float lg[16];
    const float4* lp = (const float4*)(L + (size_t)t * N_EXP);
#pragma unroll
    for (int q = 0; q < 4; q++) {
        float4 v = lp[q];
        lg[q * 4 + 0] = v.x; lg[q * 4 + 1] = v.y; lg[q * 4 + 2] = v.z; lg[q * 4 + 3] = v.w;
    }
    float best = -1e30f, sec = -1e30f; int bi = 0, si = 0;
#pragma unroll
    for (int j = 0; j < 16; j++) {
        float lj = lg[j];
        if (lj > best) { sec = best; si = bi; best = lj; bi = j; }
        else if (lj > sec) { sec = lj; si = j; }
    }
    float w1 = 1.f / (1.f + __expf(sec - best));
    sel[t * 2] = bi; sel[t * 2 + 1] = si;
    rw[t * 2] = w1;  rw[t * 2 + 1] = 1.f - w1;
    atomicAdd(&lc[bi], 1);
    atomicAdd(&lc[si], 1);
    __syncthreads();
    if (tid < N_EXP) atomicAdd(&counts[tid], lc[tid]);
}

// ---------------- fused route: prefix scan + tile list + scatter (1 block, 256 thr) ----
// Replaces prefix_kernel + scatter_kernel. Cursors live in LDS; slot order within an
// expert is arbitrary (as before), so output semantics unchanged.
__global__ __launch_bounds__(256) void route_kernel(
    const int* __restrict__ counts, const int* __restrict__ sel,
    const float* __restrict__ rwin, int* __restrict__ offsets,
    int* __restrict__ btok, float* __restrict__ bw, int* __restrict__ pos,
    int* __restrict__ tiles) {
    __shared__ int ts[17];
    __shared__ int cnt16[16];
    __shared__ int cur[16];
    const int tid = threadIdx.x;
    if (tid == 0) {
        int s = 0, t = 64;
        for (int e = 0; e < 16; e++) {
            int c = counts[e];
            cnt16[e] = c; cur[e] = s;
            offsets[e] = s; s += c;
            ts[e] = t; t += (c + 127) >> 7;
        }
        offsets[16] = s;                 // 16384
        offsets[17] = s + T_TOK;         // 24576
        ts[16] = t;                      // ntot
    }
    __syncthreads();
    // tile list (shared tiles [0,64), then expert tiles contiguous; pad -1)
    if (tid < 16) {
        int t0 = ts[tid], M = cnt16[tid];
        for (int m0 = 0, k = 0; m0 < M; m0 += 128, k++) tiles[t0 + k] = (tid << 20) | m0;
    } else if (tid == 16) {
        for (int k = 0; k < 64; k++) tiles[k] = (16 << 20) | (k * 128);
    }
    for (int j = ts[16] + tid; j < MAX_TILES; j += 256) tiles[j] = -1;
    // scatter via LDS cursors
    for (int t = tid; t < T_TOK; t += 256) {
#pragma unroll
        for (int k = 0; k < TOPK; k++) {
            int e = sel[t * 2 + k];
            int p = atomicAdd(&cur[e], 1);
            btok[p] = t;
            bw[p] = rwin[t * 2 + k];
            pos[t * 2 + k] = p;
        }
        btok[NSLOT + t] = t;     // shared bucket: identity
        bw[NSLOT + t] = 1.f;
    }
}

// XCD-chunked (tile, n0) decode
__device__ __forceinline__ void xcd_tile_map(int g, int& ti, int& n0i) {
    const int x = g & 7;
    const int q = g >> 3;
    ti  = x * XCD_TILES + (q >> 3);
    n0i = q & 7;
}

// counted-vmcnt barrier pair: raw s_barrier does NOT drain vmcnt -> prefetch
// stays in flight across the barrier.
#define WAITV4_BAR() do { \
    asm volatile("s_waitcnt vmcnt(4)" ::: "memory"); \
    __builtin_amdgcn_s_barrier(); } while (0)
#define WAITV0_BAR() do { \
    asm volatile("s_waitcnt vmcnt(0)" ::: "memory"); \
    __builtin_amdgcn_s_barrier(); } while (0)

// ---------------- fused gate_up + SiLU*up*bw: 2-buffer counted-vmcnt, XOR-swizzled LDS
// (byte-identical to the r8 run: 89.4 us, MfmaUtil 25%, conflicts 0)
__global__ __launch_bounds__(256, 4) void gemm_gateup_act(
    const f16* __restrict__ X,        // [T,1024]
    const f16* __restrict__ W,        // [17,1024,1024]
    const float* __restrict__ bias,   // [17,1024]
    const float* __restrict__ bw,     // [24576]
    f16* __restrict__ ACT,            // [24576,512]
    const int* __restrict__ offsets,  // [18]
    const int* __restrict__ btok,     // [24576]
    const int* __restrict__ tiles) {  // [MAX_TILES]
    constexpr int K = H_DIM;
    constexpr int NT = K / 32;        // 32 K-steps
    int ti, n0i;
    xcd_tile_map(blockIdx.x, ti, n0i);
    const int td = tiles[ti];
    if (td < 0) return;
    const int e  = td >> 20;
    const int m0 = td & 0xFFFFF;
    const int n0 = n0i * 64;
    const int base = offsets[e];
    const int M = offsets[e + 1] - base;

    const f16* Wb   = W + (size_t)e * 1024 * K;
    const float* bb = bias + (size_t)e * 1024;

    __shared__ f16 As[2][128 * 32];   // 16 KB
    __shared__ f16 Bg[2][64 * 32];    //  8 KB
    __shared__ f16 Bu[2][64 * 32];    //  8 KB -> 32 KB, 5 blocks/CU

    const int tid  = threadIdx.x;
    const int wave = tid >> 6;
    const int lane = tid & 63;
    const int srow = lane >> 2;                       // 0..15
    const int csw  = ((lane & 3) ^ ((srow >> 1) & 3)) * 8;

    int ar0 = m0 + wave * 32 + srow;
    int ar1 = ar0 + 16;
    int r0 = min(ar0, M - 1), r1 = min(ar1, M - 1);
    const f16* ap0 = X + (size_t)btok[base + r0] * K + csw;
    const f16* ap1 = X + (size_t)btok[base + r1] * K + csw;
    const int brow = n0 + wave * 16 + srow;
    const f16* bg0 = Wb + (size_t)brow * K + csw;
    const f16* bu0 = bg0 + (size_t)512 * K;
    f16* la0 = &As[0][(wave * 32) * 32];
    f16* la1 = la0 + 16 * 32;
    f16* lg0 = &Bg[0][(wave * 16) * 32];
    f16* lu0 = &Bu[0][(wave * 16) * 32];
    constexpr int AST = 128 * 32;
    constexpr int BST = 64 * 32;

    const int wm = (wave >> 1) * 64;
    const int wn = (wave & 1) * 32;
    const int qm = lane & 15;
    const int quad = lane >> 4;
    const int qsw = (quad ^ ((qm >> 1) & 3)) * 8;

    f32x4 accg[4][2], accu[4][2];
#pragma unroll
    for (int i = 0; i < 4; i++)
#pragma unroll
        for (int j = 0; j < 2; j++) {
            accg[i][j] = (f32x4){0.f, 0.f, 0.f, 0.f};
            accu[i][j] = (f32x4){0.f, 0.f, 0.f, 0.f};
        }

#define GU_STAGE(b) do { \
    __builtin_amdgcn_global_load_lds(GPTR(ap0), LPTR(la0 + (b) * AST), 16, 0, 0); \
    __builtin_amdgcn_global_load_lds(GPTR(ap1), LPTR(la1 + (b) * AST), 16, 0, 0); \
    __builtin_amdgcn_global_load_lds(GPTR(bg0), LPTR(lg0 + (b) * BST), 16, 0, 0); \
    __builtin_amdgcn_global_load_lds(GPTR(bu0), LPTR(lu0 + (b) * BST), 16, 0, 0); \
    ap0 += 32; ap1 += 32; bg0 += 32; bu0 += 32; } while (0)

#define GU_COMPUTE(b) do { \
    f16x8 af[4], gf[2], uf[2]; \
    _Pragma("unroll") \
    for (int i = 0; i < 4; i++) af[i] = *(const f16x8*)&As[b][(wm + i * 16 + qm) * 32 + qsw]; \
    _Pragma("unroll") \
    for (int j = 0; j < 2; j++) { \
        gf[j] = *(const f16x8*)&Bg[b][(wn + j * 16 + qm) * 32 + qsw]; \
        uf[j] = *(const f16x8*)&Bu[b][(wn + j * 16 + qm) * 32 + qsw]; \
    } \
    _Pragma("unroll") \
    for (int i = 0; i < 4; i++) \
        _Pragma("unroll") \
        for (int j = 0; j < 2; j++) { \
            accg[i][j] = __builtin_amdgcn_mfma_f32_16x16x32_f16(af[i], gf[j], accg[i][j], 0, 0, 0); \
            accu[i][j] = __builtin_amdgcn_mfma_f32_16x16x32_f16(af[i], uf[j], accu[i][j], 0, 0, 0); \
        } } while (0)

    GU_STAGE(0);                        // tile 0 in flight
    for (int t = 0; t < NT; t += 2) {
        __builtin_amdgcn_s_barrier();   // all waves done reading buf1
        GU_STAGE(1);                    // tile t+1 (stays in flight across barriers)
        WAITV4_BAR();                   // tile t landed everywhere
        GU_COMPUTE(0);                  // tile t
        __builtin_amdgcn_s_barrier();   // all waves done reading buf0
        if (t + 2 < NT) {
            GU_STAGE(0);                // tile t+2
            WAITV4_BAR();               // tile t+1 landed
        } else {
            WAITV0_BAR();               // last tile landed
        }
        GU_COMPUTE(1);                  // tile t+1
    }

    // epilogue: act = silu(g+bg)*(u+bu)*bw  (C/D: col=lane&15, row=quad*4+reg)
#pragma unroll
    for (int i = 0; i < 4; i++) {
#pragma unroll
        for (int j = 0; j < 2; j++) {
            const int colg = n0 + wn + j * 16 + qm;
            const float bvg = bb[colg];
            const float bvu = bb[colg + 512];
#pragma unroll
            for (int r = 0; r < 4; r++) {
                const int lr = wm + i * 16 + quad * 4 + r;
                const int m = m0 + lr;
                if (m < M) {
                    float g = accg[i][j][r] + bvg;
                    float u = accu[i][j][r] + bvu;
                    float sl = g / (1.f + __expf(-g));
                    ACT[(size_t)(base + m) * 512 + colg] = (f16)(sl * u * bw[base + m]);
                }
            }
        }
    }
}

// ---------------- down GEMM 128x128: counted-vmcnt pipeline, f16 DOWN stores ----------------
__global__ __launch_bounds__(256, 4) void gemm_down(
    const f16* __restrict__ ACT,      // [24576,512]
    const f16* __restrict__ W,        // [17,1024,512]
    f16* __restrict__ DOWN,           // [24576,1024]
    const int* __restrict__ offsets,
    const int* __restrict__ tiles) {
    constexpr int K = I_DIM;  // 512
    constexpr int NT = K / 32;        // 16 K-steps
    int ti, n0i;
    xcd_tile_map(blockIdx.x, ti, n0i);
    const int td = tiles[ti];
    if (td < 0) return;
    const int e  = td >> 20;
    const int m0 = td & 0xFFFFF;
    const int n0 = n0i * 128;
    const int base = offsets[e];
    const int M = offsets[e + 1] - base;

    const f16* Wb = W + (size_t)e * 1024 * K;

    __shared__ f16 As[2][128 * 32];   // 16 KB
    __shared__ f16 Bs[2][128 * 32];   // 16 KB -> 32 KB, 5 blocks/CU

    const int tid  = threadIdx.x;
    const int wave = tid >> 6;
    const int lane = tid & 63;
    const int srow = lane >> 2;
    const int csw  = ((lane & 3) ^ ((srow >> 1) & 3)) * 8;

    int ar0 = m0 + wave * 32 + srow;
    int ar1 = ar0 + 16;
    int r0 = min(ar0, M - 1), r1 = min(ar1, M - 1);
    const f16* ap0 = ACT + (size_t)(base + r0) * K + csw;
    const f16* ap1 = ACT + (size_t)(base + r1) * K + csw;
    const f16* bp0 = Wb + (size_t)(n0 + wave * 32 + srow) * K + csw;
    const f16* bp1 = bp0 + (size_t)16 * K;
    f16* la0 = &As[0][(wave * 32) * 32];  f16* la1 = la0 + 16 * 32;
    f16* lb0 = &Bs[0][(wave * 32) * 32];  f16* lb1 = lb0 + 16 * 32;
    constexpr int DST = 128 * 32;

    const int wm = (wave >> 1) * 64;
    const int wn = (wave & 1) * 64;
    const int qm = lane & 15;
    const int quad = lane >> 4;
    const int qsw = (quad ^ ((qm >> 1) & 3)) * 8;

    f32x4 acc[4][4];
#pragma unroll
    for (int i = 0; i < 4; i++)
#pragma unroll
        for (int j = 0; j < 4; j++) acc[i][j] = (f32x4){0.f, 0.f, 0.f, 0.f};

#define DN_STAGE(b) do { \
    __builtin_amdgcn_global_load_lds(GPTR(ap0), LPTR(la0 + (b) * DST), 16, 0, 0); \
    __builtin_amdgcn_global_load_lds(GPTR(ap1), LPTR(la1 + (b) * DST), 16, 0, 0); \
    __builtin_amdgcn_global_load_lds(GPTR(bp0), LPTR(lb0 + (b) * DST), 16, 0, 0); \
    __builtin_amdgcn_global_load_lds(GPTR(bp1), LPTR(lb1 + (b) * DST), 16, 0, 0); \
    ap0 += 32; ap1 += 32; bp0 += 32; bp1 += 32; } while (0)

#define DN_COMPUTE(b) do { \
    f16x8 af[4], bfr[4]; \
    _Pragma("unroll") \
    for (int i = 0; i < 4; i++) af[i]  = *(const f16x8*)&As[b][(wm + i * 16 + qm) * 32 + qsw]; \
    _Pragma("unroll") \
    for (int j = 0; j < 4; j++) bfr[j] = *(const f16x8*)&Bs[b][(wn + j * 16 + qm) * 32 + qsw]; \
    _Pragma("unroll") \
    for (int i = 0; i < 4; i++) \
        _Pragma("unroll") \
        for (int j = 0; j < 4; j++) \
            acc[i][j] = __builtin_amdgcn_mfma_f32_16x16x32_f16(af[i], bfr[j], acc[i][j], 0, 0, 0); \
    } while (0)

    DN_STAGE(0);
    for (int t = 0; t < NT; t += 2) {
        __builtin_amdgcn_s_barrier();
        DN_STAGE(1);
        WAITV4_BAR();
        DN_COMPUTE(0);
        __builtin_amdgcn_s_barrier();
        if (t + 2 < NT) {
            DN_STAGE(0);
            WAITV4_BAR();
        } else {
            WAITV0_BAR();
        }
        DN_COMPUTE(1);
    }

#pragma unroll
    for (int i = 0; i < 4; i++) {
#pragma unroll
        for (int j = 0; j < 4; j++) {
            const int col = n0 + wn + j * 16 + qm;
#pragma unroll
            for (int r = 0; r < 4; r++) {
                const int lr = wm + i * 16 + quad * 4 + r;
                const int m = m0 + lr;
                if (m < M) DOWN[(size_t)(base + m) * 1024 + col] = (f16)acc[i][j][r];
            }
        }
    }
}

// ---------------- combine: out[t] = DOWN[16384+t] + DOWN[p1] + DOWN[p2], f16x8 loads ----
__global__ void combine_kernel(const f16* __restrict__ DOWN, const int* __restrict__ pos,
                               float* __restrict__ OUT) {
    int idx = blockIdx.x * blockDim.x + threadIdx.x;
    int t = idx >> 7;             // 128 threads per token (1024 cols / 8)
    int c = (idx & 127) * 8;
    int p1 = pos[t * 2], p2 = pos[t * 2 + 1];
    f16x8 a = *(const f16x8*)(DOWN + (size_t)(NSLOT + t) * 1024 + c);
    f16x8 b = *(const f16x8*)(DOWN + (size_t)p1 * 1024 + c);
    f16x8 d = *(const f16x8*)(DOWN + (size_t)p2 * 1024 + c);
    float4 o0, o1;
    o0.x = (float)a[0] + (float)b[0] + (float)d[0];
    o0.y = (float)a[1] + (float)b[1] + (float)d[1];
    o0.z = (float)a[2] + (float)b[2] + (float)d[2];
    o0.w = (float)a[3] + (float)b[3] + (float)d[3];
    o1.x = (float)a[4] + (float)b[4] + (float)d[4];
    o1.y = (float)a[5] + (float)b[5] + (float)d[5];
    o1.z = (float)a[6] + (float)b[6] + (float)d[6];
    o1.w = (float)a[7] + (float)b[7] + (float)d[7];
    *(float4*)(OUT + (size_t)t * 1024 + c) = o0;
    *(float4*)(OUT + (size_t)t * 1024 + c + 4) = o1;
}

// ---------------- host launch ----------------
extern "C" void kernel_launch(void* const* d_in, const int* in_sizes, int n_in,
                              void* d_out, int out_size, void* d_ws, size_t ws_size,
                              hipStream_t stream) {
    const float* x    = (const float*)d_in[0];   // [8192,1024]
    const float* gw   = (const float*)d_in[1];   // [16,1024]
    const float* wgu  = (const float*)d_in[2];   // [16,1024,1024]
    const float* bgu  = (const float*)d_in[3];   // [16,1024]
    const float* wd   = (const float*)d_in[4];   // [16,1024,512]
    const float* wsgu = (const float*)d_in[5];   // [1024,1024]
    const float* bsgu = (const float*)d_in[6];   // [1024]
    const float* wsd  = (const float*)d_in[7];   // [1024,512]
    float* out = (float*)d_out;

    char* ws = (char*)d_ws;
    size_t off = 0;
    auto take = [&](size_t b) { char* p = ws + off; off = (off + b + 255) & ~(size_t)255; return p; };
    f16* x_h    = (f16*)take((size_t)T_TOK * H_DIM * 2);
    f16* x_l    = (f16*)take((size_t)T_TOK * H_DIM * 2);
    f16* gw_h   = (f16*)take((size_t)N_EXP * H_DIM * 2);
    f16* gw_l   = (f16*)take((size_t)N_EXP * H_DIM * 2);
    f16* wguA   = (f16*)take((size_t)N_ALL * 1024 * H_DIM * 2);   // [17,1024,1024]
    f16* wdA    = (f16*)take((size_t)N_ALL * 1024 * I_DIM * 2);   // [17,1024,512]
    float* biasA = (float*)take((size_t)N_ALL * 1024 * 4);        // [17,1024]
    f16* act    = (f16*)take((size_t)NSLOT_ALL * I_DIM * 2);      // [24576,512]
    f16* down   = (f16*)take((size_t)NSLOT_ALL * 1024 * 2);       // [24576,1024]
    float* logits = (float*)take((size_t)T_TOK * N_EXP * 4);
    int*   sel    = (int*)take((size_t)NSLOT * 4);
    float* rw     = (float*)take((size_t)NSLOT * 4);
    int*   btok   = (int*)take((size_t)NSLOT_ALL * 4);
    float* bw     = (float*)take((size_t)NSLOT_ALL * 4);
    int*   pos    = (int*)take((size_t)NSLOT * 4);
    int*   counts = (int*)take(64);
    int*   offs   = (int*)take(128);
    int*   tiles  = (int*)take(MAX_TILES * 4);

    // 1) all casts/splits/copies/zeroing
    prep_kernel<<<PREP_BLOCKS, 256, 0, stream>>>(x, gw, wgu, wsgu, wd, wsd, bgu, bsgu,
                                                 x_h, x_l, gw_h, gw_l, wguA, wdA, biasA, counts);

    // 2) routing: logits, top-2, then fused prefix+tiles+scatter
    logits_kernel<<<T_TOK / 64, 256, 0, stream>>>(x_h, x_l, gw_h, gw_l, logits);
    topk_kernel<<<T_TOK / 256, 256, 0, stream>>>(logits, sel, rw, counts);
    route_kernel<<<1, 256, 0, stream>>>(counts, sel, rw, offs, btok, bw, pos, tiles);

    // 3) fused gate_up + SiLU*up*bw -> ACT (XCD-chunked, counted-vmcnt pipeline)
    gemm_gateup_act<<<dim3(MAX_TILES * 8, 1, 1), 256, 0, stream>>>(x_h, wguA, biasA, bw, act, offs, btok, tiles);

    // 4) down GEMM (128x128, counted-vmcnt pipeline) -> DOWN (f16, coalesced)
    gemm_down<<<dim3(MAX_TILES * 8, 1, 1), 256, 0, stream>>>(act, wdA, down, offs, tiles);

    // 5) combine (f16x8-vectorized)
    combine_kernel<<<T_TOK * 1024 / 8 / 256, 256, 0, stream>>>(down, pos, out);
}